// Round 16
// baseline (222.185 us; speedup 1.0000x reference)
//
#include <hip/hip_runtime.h>
#include <hip/hip_fp16.h>

#define NN 50000
#define NE 800000
#define SLOPE 0.2f
#define SCAN_B 196   // ceil(NN/256)
#define ECAP 64      // cached edges per wave in node_fused

typedef _Float16 half8 __attribute__((ext_vector_type(8)));
typedef float f32x4 __attribute__((ext_vector_type(4)));
typedef unsigned int u32x4 __attribute__((ext_vector_type(4)));

__device__ __forceinline__ float lrelu(float v) { return v >= 0.f ? v : SLOPE * v; }
// monotonic float<->uint encoding for atomicMax on signed floats
__device__ __forceinline__ unsigned int f2u(float f) {
    unsigned int b = __float_as_uint(f);
    return (b & 0x80000000u) ? ~b : (b | 0x80000000u);
}
__device__ __forceinline__ float u2f(unsigned int u) {
    return __uint_as_float((u & 0x80000000u) ? (u & 0x7fffffffu) : ~u);
}
// NT load of packed {e,s} (read-once stream: keep out of L2, preserve it for H16)
__device__ __forceinline__ int2 ldnt_es(const int2* p) {
    unsigned long long v = __builtin_nontemporal_load((const unsigned long long*)p);
    int2 r;
    r.x = (int)(unsigned)(v & 0xffffffffu);   // e (low word)
    r.y = (int)(unsigned)(v >> 32);           // s (high word)
    return r;
}

// ---------------- fused prep: zero counts + gmax init + WTaug for both layers ----------------
__global__ __launch_bounds__(256) void prep_all(
    const float* __restrict__ W1, const float* __restrict__ as1, const float* __restrict__ ad1,
    __half* __restrict__ WT1,
    const float* __restrict__ W2, const float* __restrict__ as2, const float* __restrict__ ad2,
    __half* __restrict__ WT2,
    int* __restrict__ counts, unsigned int* __restrict__ gm1, unsigned int* __restrict__ gm2)
{
    const int t0 = blockIdx.x * 256 + threadIdx.x;
    const int stride = gridDim.x * 256;
    for (int i = t0; i < NN; i += stride) counts[i] = 0;
    if (t0 < 8) { gm1[t0] = f2u(-1e30f); gm2[t0] = f2u(-1e30f); }
    #pragma unroll
    for (int layer = 0; layer < 2; ++layer) {
        const float* W = layer ? W2 : W1;
        const float* as_ = layer ? as2 : as1;
        const float* ad_ = layer ? ad2 : ad1;
        __half* WT = layer ? WT2 : WT1;
        for (int idx = t0; idx < 1024; idx += stride) {   // (k,h) aug rows
            const int k = idx >> 3, h = idx & 7;
            float s1 = 0.f, s2 = 0.f;
            #pragma unroll
            for (int c = 0; c < 16; ++c) {
                const float w = W[k * 128 + h * 16 + c];
                s1 += w * as_[h * 16 + c];
                s2 += w * ad_[h * 16 + c];
            }
            WT[(size_t)(128 + h) * 128 + k] = (__half)s1;
            WT[(size_t)(136 + h) * 128 + k] = (__half)s2;
        }
        for (int idx = t0; idx < 16384; idx += stride) {  // transpose W
            const int k = idx >> 7, c = idx & 127;
            WT[(size_t)c * 128 + k] = (__half)W[idx];
        }
    }
}

// ---------------- MFMA GEMM (+ optional fused CSR placement) ----------------
// H16 = f16(X @ W), asrc/adst fused as cols 128..143. WT staged in LDS
// (rows padded 128->136 halves). X rows loaded NON-TEMPORAL (read-once stream;
// keeps L2 for the H16 writes node_fused will re-read). gmax via LDS-staged
// block max (round-12 lesson: per-wave global atomics cost ~60us).
template<bool F32IN, bool DOPLACE>
__global__ __launch_bounds__(256) void mfma_gemm(
    const void* __restrict__ Xin, const __half* __restrict__ WT,
    __half* __restrict__ H16, float* __restrict__ asrc, float* __restrict__ adst,
    unsigned int* __restrict__ gmaxE,
    const int* __restrict__ srcA, const int* __restrict__ dstA,
    const int* __restrict__ rank, const int* __restrict__ offA,
    int2* __restrict__ csrES)
{
    __shared__ __half WTs[144 * 136];
    __shared__ unsigned int smax[8];
    const int t = threadIdx.x;
    const int lane = t & 63;
    const int w = t >> 6;
    const int r16 = lane & 15;
    const int g = lane >> 4;
    const int rowStrip = blockIdx.x * 64 + w * 16;
    const int rowm = min(rowStrip + r16, NN - 1);

    // stage WT: 144x128 halves = 2304 half8, 9 per thread, coalesced
    #pragma unroll
    for (int k = 0; k < 9; ++k) {
        const int flat = (t + k * 256) * 8;
        const int row = flat >> 7, col = flat & 127;
        *(half8*)&WTs[row * 136 + col] = *(const half8*)&WT[flat];
    }
    if (t < 8) smax[t] = f2u(-1e30f);

    // fused placement: compute (pos, v) early; latency hides under GEMM
    int ppos[DOPLACE ? 4 : 1];
    unsigned long long pval[DOPLACE ? 4 : 1];
    if constexpr (DOPLACE) {
        const int eBase = blockIdx.x * 1024;
        #pragma unroll
        for (int k = 0; k < 4; ++k) {
            const int e = eBase + k * 256 + t;
            ppos[k] = -1;
            if (e < NE) {
                int s = __builtin_nontemporal_load(&srcA[e]);
                int d = __builtin_nontemporal_load(&dstA[e]);
                int r = __builtin_nontemporal_load(&rank[e]);
                if ((unsigned)s >= NN) s = 0;
                if ((unsigned)d >= NN) d = 0;
                ppos[k] = offA[d] + r;
                pval[k] = ((unsigned long long)(unsigned)s << 32) | (unsigned)e;
            }
        }
    }

    half8 afr[4];
    if constexpr (F32IN) {
        const float* xr = (const float*)Xin + (size_t)rowm * 128;
        #pragma unroll
        for (int ks = 0; ks < 4; ++ks) {
            const int k0 = ks * 32 + 8 * g;
            const f32x4 p = __builtin_nontemporal_load((const f32x4*)&xr[k0]);
            const f32x4 q = __builtin_nontemporal_load((const f32x4*)&xr[k0 + 4]);
            half8 a;
            a[0] = (_Float16)p.x; a[1] = (_Float16)p.y; a[2] = (_Float16)p.z; a[3] = (_Float16)p.w;
            a[4] = (_Float16)q.x; a[5] = (_Float16)q.y; a[6] = (_Float16)q.z; a[7] = (_Float16)q.w;
            afr[ks] = a;
        }
    } else {
        const __half* xr = (const __half*)Xin + (size_t)rowm * 128;
        #pragma unroll
        for (int ks = 0; ks < 4; ++ks) {
            afr[ks] = __builtin_nontemporal_load((const half8*)&xr[ks * 32 + 8 * g]);
        }
    }
    __syncthreads();

    for (int ct = 0; ct < 9; ++ct) {
        f32x4 acc = {0.f, 0.f, 0.f, 0.f};
        const __half* wrow = &WTs[(ct * 16 + r16) * 136 + 8 * g];
        #pragma unroll
        for (int ks = 0; ks < 4; ++ks) {
            const half8 b = *(const half8*)&wrow[ks * 32];
            acc = __builtin_amdgcn_mfma_f32_16x16x32_f16(afr[ks], b, acc, 0, 0, 0);
        }
        if (ct < 8) {
            #pragma unroll
            for (int rr = 0; rr < 4; ++rr) {
                const int r = rowStrip + 4 * g + rr;
                if (r < NN) H16[(size_t)r * 128 + ct * 16 + r16] = (__half)acc[rr];
            }
        } else {
            float lmax = fmaxf(fmaxf(acc[0], acc[1]), fmaxf(acc[2], acc[3]));
            #pragma unroll
            for (int rr = 0; rr < 4; ++rr) {
                const int r = rowStrip + 4 * g + rr;
                if (r < NN) {
                    if (r16 < 8) asrc[(size_t)r * 8 + r16] = acc[rr];
                    else         adst[(size_t)r * 8 + (r16 - 8)] = acc[rr];
                }
            }
            lmax = fmaxf(lmax, __shfl_xor(lmax, 16));
            lmax = fmaxf(lmax, __shfl_xor(lmax, 32));
            if (g == 0 && r16 < 8) atomicMax(&smax[r16], f2u(lmax));   // LDS atomic
        }
    }

    if constexpr (DOPLACE) {
        #pragma unroll
        for (int k = 0; k < 4; ++k) {
            if (ppos[k] >= 0) {
                __builtin_nontemporal_store(pval[k], (unsigned long long*)&csrES[ppos[k]]);
            }
        }
    }
    __syncthreads();
    if (t < 8) atomicMax(&gmaxE[t], smax[t]);   // 8 global atomics per block
}

// ---------------- CSR build ----------------
__global__ __launch_bounds__(256) void hist_rank(
    const int* __restrict__ dst, int* __restrict__ counts, int* __restrict__ rank) {
    int e = blockIdx.x * 256 + threadIdx.x;
    if (e >= NE) return;
    int d = __builtin_nontemporal_load(&dst[e]);
    if ((unsigned)d >= NN) d = 0;
    int r = atomicAdd(&counts[d], 1);
    __builtin_nontemporal_store(r, &rank[e]);
}

__global__ __launch_bounds__(256) void block_sum(const int* __restrict__ counts,
                                                 int* __restrict__ bsum) {
    __shared__ int red[256];
    int t = threadIdx.x, i = blockIdx.x * 256 + t;
    red[t] = (i < NN) ? counts[i] : 0;
    __syncthreads();
    for (int s = 128; s > 0; s >>= 1) {
        if (t < s) red[t] += red[t + s];
        __syncthreads();
    }
    if (t == 0) bsum[blockIdx.x] = red[0];
}

__global__ __launch_bounds__(256) void scan_bsum(const int* __restrict__ bsum,
                                                 int* __restrict__ boff) {
    __shared__ int sh[256];
    int t = threadIdx.x;
    int v = (t < SCAN_B) ? bsum[t] : 0;
    sh[t] = v;
    __syncthreads();
    for (int d = 1; d < 256; d <<= 1) {
        int u = (t >= d) ? sh[t - d] : 0;
        __syncthreads();
        sh[t] += u;
        __syncthreads();
    }
    if (t < SCAN_B) boff[t] = sh[t] - v;   // exclusive
}

__global__ __launch_bounds__(256) void scan_final(
    const int* __restrict__ counts, const int* __restrict__ boff,
    int* __restrict__ off)
{
    __shared__ int sh[256];
    int t = threadIdx.x, i = blockIdx.x * 256 + t;
    int v = (i < NN) ? counts[i] : 0;
    sh[t] = v;
    __syncthreads();
    for (int d = 1; d < 256; d <<= 1) {
        int u = (t >= d) ? sh[t - d] : 0;
        __syncthreads();
        sh[t] += u;
        __syncthreads();
    }
    if (i < NN) {
        int o = boff[blockIdx.x] + sh[t] - v;
        off[i] = o;
        if (i == NN - 1) off[NN] = o + v;
    }
}

// H-row gather + FMA helper
__device__ __forceinline__ void gather_fma(
    const __half* __restrict__ H16, int sk, int ql, float pm,
    float4& accA, float4& accB)
{
    float4 raw = *(const float4*)&H16[(size_t)sk * 128 + ql * 8];
    const __half2* ph = (const __half2*)&raw;
    const float2 f0 = __half22float2(ph[0]);
    const float2 f1 = __half22float2(ph[1]);
    const float2 f2 = __half22float2(ph[2]);
    const float2 f3 = __half22float2(ph[3]);
    accA.x = fmaf(f0.x, pm, accA.x);
    accA.y = fmaf(f0.y, pm, accA.y);
    accA.z = fmaf(f1.x, pm, accA.z);
    accA.w = fmaf(f1.y, pm, accA.w);
    accB.x = fmaf(f2.x, pm, accB.x);
    accB.y = fmaf(f2.y, pm, accB.y);
    accB.z = fmaf(f3.x, pm, accB.z);
    accB.w = fmaf(f3.y, pm, accB.w);
}

// ---------------- SINGLE-PASS per-node softmax + aggregate (one wave per node) ----------------
// Fixed safe max M = lrelu(gmax[h] + adst[d,h]). 16 edges per iteration.
// csrES read NON-TEMPORAL (read-once stream -> preserve L2 for H16 rows).
template<typename OT, bool NTOUT>
__global__ __launch_bounds__(256) void node_fused(
    const int* __restrict__ off, const int2* __restrict__ csrES,
    const float* __restrict__ asrc, const float* __restrict__ adst,
    const unsigned int* __restrict__ gmaxE,
    const __half* __restrict__ H16, const float* __restrict__ bias,
    float* __restrict__ alpha, OT* __restrict__ out)
{
    __shared__ float pcache[4][ECAP * 8];   // per-wave unnormalized exp [i][h]
    __shared__ int2  scache[4][ECAP];       // per-wave {e, s}
    const int w = threadIdx.x >> 6;         // wave within block
    int wid = (blockIdx.x * 256 + threadIdx.x) >> 6;
    if (wid >= NN) return;
    const int lane = threadIdx.x & 63;
    const int n = wid;
    const int p0 = off[n], p1 = off[n + 1];
    const int deg = p1 - p0;
    const int h = lane & 7;      // head (stat lanes: lane = el*8+h)
    const int el = lane >> 3;    // edge-local slot 0..7
    const float ad = adst[n * 8 + h];
    const float M = lrelu(u2f(gmaxE[h]) + ad);   // safe upper bound for this node/head

    const int q  = lane >> 4;    // gather quarter
    const int ql = lane & 15;    // channels ql*8..ql*8+7
    const int hq = ql >> 1;      // head of this channel group

    float l = 0.f;
    float4 accA = make_float4(0.f, 0.f, 0.f, 0.f);
    float4 accB = make_float4(0.f, 0.f, 0.f, 0.f);

    if (deg > 0) {
        const int pEnd = p1 - 1;
        int2  esA = ldnt_es(&csrES[min(p0 + el, pEnd)]);        // sub-chunk A prefetch
        int2  esB = ldnt_es(&csrES[min(p0 + 8 + el, pEnd)]);    // sub-chunk B prefetch
        float avA = asrc[(size_t)esA.y * 8 + h];
        float avB = asrc[(size_t)esB.y * 8 + h];
        for (int base = 0; base < deg; base += 16) {
            int2 esA_nx = ldnt_es(&csrES[min(p0 + base + 16 + el, pEnd)]);
            int2 esB_nx = ldnt_es(&csrES[min(p0 + base + 24 + el, pEnd)]);
            const int iA = base + el, iB = base + 8 + el;
            const int sA = esA.y, sB = esB.y;
            float pA = 0.f, pB = 0.f;
            if (iA < deg) {
                pA = __expf(lrelu(avA + ad) - M);
                l += pA;
                if (iA < ECAP) {
                    pcache[w][iA * 8 + h] = pA;
                    if (h == 0) scache[w][iA] = esA;
                }
            }
            if (iB < deg) {
                pB = __expf(lrelu(avB + ad) - M);
                l += pB;
                if (iB < ECAP) {
                    pcache[w][iB * 8 + h] = pB;
                    if (h == 0) scache[w][iB] = esB;
                }
            }
            const int cntA = min(8, deg - base);                 // >= 1
            const int cntB = min(8, max(0, deg - base - 8));     // may be 0
            {   // A step 0 (always)
                const int kc = min(q, cntA - 1);
                const float pk = __shfl(pA, kc * 8 + hq);
                const int   sk = __shfl(sA, kc * 8);
                gather_fma(H16, sk, ql, (q < cntA) ? pk : 0.f, accA, accB);
            }
            if (cntA > 4) {   // wave-uniform
                const int kw = 4 + q, kc = min(kw, cntA - 1);
                const float pk = __shfl(pA, kc * 8 + hq);
                const int   sk = __shfl(sA, kc * 8);
                gather_fma(H16, sk, ql, (kw < cntA) ? pk : 0.f, accA, accB);
            }
            if (cntB > 0) {   // wave-uniform
                const int kc = min(q, cntB - 1);
                const float pk = __shfl(pB, kc * 8 + hq);
                const int   sk = __shfl(sB, kc * 8);
                gather_fma(H16, sk, ql, (q < cntB) ? pk : 0.f, accA, accB);
            }
            if (cntB > 4) {   // wave-uniform
                const int kw = 4 + q, kc = min(kw, cntB - 1);
                const float pk = __shfl(pB, kc * 8 + hq);
                const int   sk = __shfl(sB, kc * 8);
                gather_fma(H16, sk, ql, (kw < cntB) ? pk : 0.f, accA, accB);
            }
            avA = asrc[(size_t)esA_nx.y * 8 + h];
            avB = asrc[(size_t)esB_nx.y * 8 + h];
            esA = esA_nx;
            esB = esB_nx;
        }
    }
    // sum l across the 8 edge-slot groups
    l += __shfl_xor(l, 8);
    l += __shfl_xor(l, 16);
    l += __shfl_xor(l, 32);
    const float inv = 1.f / (l + 1e-16f);

    // alpha writes: cached edges from LDS (no shfl inside -> divergence safe)
    for (int i = el; i < deg && i < ECAP; i += 8) {
        int2 es = scache[w][i];
        __builtin_nontemporal_store(pcache[w][i * 8 + h] * inv,
                                    &alpha[(size_t)es.x * 8 + h]);
    }
    for (int i = ECAP + el; i < deg; i += 8) {         // rare overflow tail
        int2 es = ldnt_es(&csrES[p0 + i]);
        float v = lrelu(asrc[es.y * 8 + h] + ad);
        __builtin_nontemporal_store(__expf(v - M) * inv,
                                    &alpha[(size_t)es.x * 8 + h]);
    }

    // combine quarters, normalize, bias, store
    const float invH = __shfl(inv, hq);    // inv for this channel group's head
    accA.x += __shfl_xor(accA.x, 16); accA.x += __shfl_xor(accA.x, 32);
    accA.y += __shfl_xor(accA.y, 16); accA.y += __shfl_xor(accA.y, 32);
    accA.z += __shfl_xor(accA.z, 16); accA.z += __shfl_xor(accA.z, 32);
    accA.w += __shfl_xor(accA.w, 16); accA.w += __shfl_xor(accA.w, 32);
    accB.x += __shfl_xor(accB.x, 16); accB.x += __shfl_xor(accB.x, 32);
    accB.y += __shfl_xor(accB.y, 16); accB.y += __shfl_xor(accB.y, 32);
    accB.z += __shfl_xor(accB.z, 16); accB.z += __shfl_xor(accB.z, 32);
    accB.w += __shfl_xor(accB.w, 16); accB.w += __shfl_xor(accB.w, 32);
    if (q == 0) {
        const float4 bva = *(const float4*)&bias[ql * 8];
        const float4 bvb = *(const float4*)&bias[ql * 8 + 4];
        const float o0 = accA.x * invH + bva.x, o1 = accA.y * invH + bva.y;
        const float o2 = accA.z * invH + bva.z, o3 = accA.w * invH + bva.w;
        const float o4 = accB.x * invH + bvb.x, o5 = accB.y * invH + bvb.y;
        const float o6 = accB.z * invH + bvb.z, o7 = accB.w * invH + bvb.w;
        if constexpr (sizeof(OT) == 4) {
            if constexpr (NTOUT) {
                f32x4 oa = {o0, o1, o2, o3}, ob = {o4, o5, o6, o7};
                __builtin_nontemporal_store(oa, (f32x4*)&out[(size_t)n * 128 + ql * 8]);
                __builtin_nontemporal_store(ob, (f32x4*)&out[(size_t)n * 128 + ql * 8 + 4]);
            } else {
                float4 oa = {o0, o1, o2, o3}, ob = {o4, o5, o6, o7};
                *(float4*)&out[(size_t)n * 128 + ql * 8]     = oa;
                *(float4*)&out[(size_t)n * 128 + ql * 8 + 4] = ob;
            }
        } else {
            __half2 p0h = __floats2half2_rn(o0, o1);
            __half2 p1h = __floats2half2_rn(o2, o3);
            __half2 p2h = __floats2half2_rn(o4, o5);
            __half2 p3h = __floats2half2_rn(o6, o7);
            u32x4 pk = {*(unsigned*)&p0h, *(unsigned*)&p1h, *(unsigned*)&p2h, *(unsigned*)&p3h};
            if constexpr (NTOUT) {
                __builtin_nontemporal_store(pk, (u32x4*)&out[(size_t)n * 128 + ql * 8]);
            } else {
                *(u32x4*)&out[(size_t)n * 128 + ql * 8] = pk;
            }
        }
    }
}

extern "C" void kernel_launch(void* const* d_in, const int* in_sizes, int n_in,
                              void* d_out, int out_size, void* d_ws, size_t ws_size,
                              hipStream_t stream)
{
    const float* x   = (const float*)d_in[0];
    const float* W1  = (const float*)d_in[1];
    const float* as1 = (const float*)d_in[2];
    const float* ad1 = (const float*)d_in[3];
    const float* b1  = (const float*)d_in[4];
    const float* W2  = (const float*)d_in[5];
    const float* as2 = (const float*)d_in[6];
    const float* ad2 = (const float*)d_in[7];
    const float* b2  = (const float*)d_in[8];
    const int*   ei  = (const int*)d_in[9];
    const int* srcp = ei;
    const int* dstp = ei + NE;

    float* outx   = (float*)d_out;            // [NN*128]
    float* alpha1 = outx + (size_t)NN * 128;  // [NE*8]
    float* alpha2 = alpha1 + (size_t)NE * 8;  // [NE*8]

    __half* h16 = (__half*)d_ws;                        // NN*128 halves
    __half* x1h = h16 + (size_t)NN * 128;               // NN*128 halves
    __half* wt1 = x1h + (size_t)NN * 128;               // 144*128 halves
    __half* wt2 = wt1 + (size_t)144 * 128;              // 144*128 halves
    float* asrc = (float*)(wt2 + (size_t)144 * 128);    // NN*8
    float* adst = asrc + (size_t)NN * 8;                // NN*8
    int* counts = (int*)(adst + (size_t)NN * 8);        // NN
    int* off    = counts + NN;                           // NN+1
    int* rank   = off + NN + 1;                          // NE
    int2* csrES = (int2*)(rank + NE);                    // NE int2
    int* bsum   = (int*)(csrES + NE);                    // SCAN_B
    int* boff   = bsum + SCAN_B;                         // SCAN_B
    unsigned int* gm1 = (unsigned int*)(boff + SCAN_B);  // 8
    unsigned int* gm2 = gm1 + 8;                         // 8

    int gemmGrid = (NN + 63) / 64;         // 782; also covers 782*1024 >= NE placements
    int nodeGrid = (NN + 3) / 4;           // 4 waves (nodes) per 256-thread block
    int edgeGrid = (NE + 255) / 256;

    // ---- fused prep (zero counts + gmax init + both WTaug) + CSR build ----
    prep_all<<<SCAN_B, 256, 0, stream>>>(W1, as1, ad1, wt1, W2, as2, ad2, wt2, counts, gm1, gm2);
    hist_rank<<<edgeGrid, 256, 0, stream>>>(dstp, counts, rank);
    block_sum<<<SCAN_B, 256, 0, stream>>>(counts, bsum);
    scan_bsum<<<1, 256, 0, stream>>>(bsum, boff);
    scan_final<<<SCAN_B, 256, 0, stream>>>(counts, boff, off);

    // ---- layer 1 (gemm fused with CSR placement) ----
    mfma_gemm<true, true><<<gemmGrid, 256, 0, stream>>>(
        x, wt1, h16, asrc, adst, gm1, srcp, dstp, rank, off, csrES);
    node_fused<__half, false><<<nodeGrid, 256, 0, stream>>>(off, csrES, asrc, adst, gm1, h16, b1, alpha1, x1h);

    // ---- layer 2 ----
    mfma_gemm<false, false><<<gemmGrid, 256, 0, stream>>>(
        x1h, wt2, h16, asrc, adst, gm2, nullptr, nullptr, nullptr, nullptr, nullptr);
    node_fused<float, true><<<nodeGrid, 256, 0, stream>>>(off, csrES, asrc, adst, gm2, h16, b2, alpha2, outx);
}

// Round 17
// 206.243 us; speedup vs baseline: 1.0773x; 1.0773x over previous
//
#include <hip/hip_runtime.h>
#include <hip/hip_fp16.h>

#define NN 50000
#define NE 800000
#define SLOPE 0.2f
#define SCAN_B 196   // ceil(NN/256)
#define ECAP 64      // cached edges per wave in node_fused

typedef _Float16 half8 __attribute__((ext_vector_type(8)));
typedef float f32x4 __attribute__((ext_vector_type(4)));
typedef unsigned int u32x4 __attribute__((ext_vector_type(4)));

__device__ __forceinline__ float lrelu(float v) { return v >= 0.f ? v : SLOPE * v; }
// monotonic float<->uint encoding for atomicMax on signed floats
__device__ __forceinline__ unsigned int f2u(float f) {
    unsigned int b = __float_as_uint(f);
    return (b & 0x80000000u) ? ~b : (b | 0x80000000u);
}
__device__ __forceinline__ float u2f(unsigned int u) {
    return __uint_as_float((u & 0x80000000u) ? (u & 0x7fffffffu) : ~u);
}

// ---------------- fused prep: zero counts + gmax init + WTaug for both layers ----------------
__global__ __launch_bounds__(256) void prep_all(
    const float* __restrict__ W1, const float* __restrict__ as1, const float* __restrict__ ad1,
    __half* __restrict__ WT1,
    const float* __restrict__ W2, const float* __restrict__ as2, const float* __restrict__ ad2,
    __half* __restrict__ WT2,
    int* __restrict__ counts, unsigned int* __restrict__ gm1, unsigned int* __restrict__ gm2)
{
    const int t0 = blockIdx.x * 256 + threadIdx.x;
    const int stride = gridDim.x * 256;
    for (int i = t0; i < NN; i += stride) counts[i] = 0;
    if (t0 < 8) { gm1[t0] = f2u(-1e30f); gm2[t0] = f2u(-1e30f); }
    #pragma unroll
    for (int layer = 0; layer < 2; ++layer) {
        const float* W = layer ? W2 : W1;
        const float* as_ = layer ? as2 : as1;
        const float* ad_ = layer ? ad2 : ad1;
        __half* WT = layer ? WT2 : WT1;
        for (int idx = t0; idx < 1024; idx += stride) {   // (k,h) aug rows
            const int k = idx >> 3, h = idx & 7;
            float s1 = 0.f, s2 = 0.f;
            #pragma unroll
            for (int c = 0; c < 16; ++c) {
                const float w = W[k * 128 + h * 16 + c];
                s1 += w * as_[h * 16 + c];
                s2 += w * ad_[h * 16 + c];
            }
            WT[(size_t)(128 + h) * 128 + k] = (__half)s1;
            WT[(size_t)(136 + h) * 128 + k] = (__half)s2;
        }
        for (int idx = t0; idx < 16384; idx += stride) {  // transpose W
            const int k = idx >> 7, c = idx & 127;
            WT[(size_t)c * 128 + k] = (__half)W[idx];
        }
    }
}

// ---------------- MFMA GEMM (+ optional fused CSR placement) ----------------
// H16 = f16(X @ W), asrc/adst fused as cols 128..143. WT staged in LDS
// (rows padded 128->136 halves: 2-way bank aliasing = free). gmax via
// LDS-staged block max (round-12 lesson: per-wave global atomics cost ~60us).
// DOPLACE: each block also places 1024 edges into csrES — (pos,v) computed
// up front so the off[d] gathers hide under the MFMA phase; NT stores at end.
template<bool F32IN, bool DOPLACE>
__global__ __launch_bounds__(256) void mfma_gemm(
    const void* __restrict__ Xin, const __half* __restrict__ WT,
    __half* __restrict__ H16, float* __restrict__ asrc, float* __restrict__ adst,
    unsigned int* __restrict__ gmaxE,
    const int* __restrict__ srcA, const int* __restrict__ dstA,
    const int* __restrict__ rank, const int* __restrict__ offA,
    int2* __restrict__ csrES)
{
    __shared__ __half WTs[144 * 136];
    __shared__ unsigned int smax[8];
    const int t = threadIdx.x;
    const int lane = t & 63;
    const int w = t >> 6;
    const int r16 = lane & 15;
    const int g = lane >> 4;
    const int rowStrip = blockIdx.x * 64 + w * 16;
    const int rowm = min(rowStrip + r16, NN - 1);

    // stage WT: 144x128 halves = 2304 half8, 9 per thread, coalesced
    #pragma unroll
    for (int k = 0; k < 9; ++k) {
        const int flat = (t + k * 256) * 8;
        const int row = flat >> 7, col = flat & 127;
        *(half8*)&WTs[row * 136 + col] = *(const half8*)&WT[flat];
    }
    if (t < 8) smax[t] = f2u(-1e30f);

    // fused placement: compute (pos, v) early; latency hides under GEMM
    int ppos[DOPLACE ? 4 : 1];
    unsigned long long pval[DOPLACE ? 4 : 1];
    if constexpr (DOPLACE) {
        const int eBase = blockIdx.x * 1024;
        #pragma unroll
        for (int k = 0; k < 4; ++k) {
            const int e = eBase + k * 256 + t;
            ppos[k] = -1;
            if (e < NE) {
                int s = srcA[e], d = dstA[e];
                if ((unsigned)s >= NN) s = 0;
                if ((unsigned)d >= NN) d = 0;
                ppos[k] = offA[d] + rank[e];
                pval[k] = ((unsigned long long)(unsigned)s << 32) | (unsigned)e;
            }
        }
    }

    half8 afr[4];
    if constexpr (F32IN) {
        const float* xr = (const float*)Xin + (size_t)rowm * 128;
        #pragma unroll
        for (int ks = 0; ks < 4; ++ks) {
            const int k0 = ks * 32 + 8 * g;
            const float4 p = *(const float4*)&xr[k0];
            const float4 q = *(const float4*)&xr[k0 + 4];
            half8 a;
            a[0] = (_Float16)p.x; a[1] = (_Float16)p.y; a[2] = (_Float16)p.z; a[3] = (_Float16)p.w;
            a[4] = (_Float16)q.x; a[5] = (_Float16)q.y; a[6] = (_Float16)q.z; a[7] = (_Float16)q.w;
            afr[ks] = a;
        }
    } else {
        const __half* xr = (const __half*)Xin + (size_t)rowm * 128;
        #pragma unroll
        for (int ks = 0; ks < 4; ++ks) {
            afr[ks] = *(const half8*)&xr[ks * 32 + 8 * g];
        }
    }
    __syncthreads();

    for (int ct = 0; ct < 9; ++ct) {
        f32x4 acc = {0.f, 0.f, 0.f, 0.f};
        const __half* wrow = &WTs[(ct * 16 + r16) * 136 + 8 * g];
        #pragma unroll
        for (int ks = 0; ks < 4; ++ks) {
            const half8 b = *(const half8*)&wrow[ks * 32];
            acc = __builtin_amdgcn_mfma_f32_16x16x32_f16(afr[ks], b, acc, 0, 0, 0);
        }
        if (ct < 8) {
            #pragma unroll
            for (int rr = 0; rr < 4; ++rr) {
                const int r = rowStrip + 4 * g + rr;
                if (r < NN) H16[(size_t)r * 128 + ct * 16 + r16] = (__half)acc[rr];
            }
        } else {
            float lmax = fmaxf(fmaxf(acc[0], acc[1]), fmaxf(acc[2], acc[3]));
            #pragma unroll
            for (int rr = 0; rr < 4; ++rr) {
                const int r = rowStrip + 4 * g + rr;
                if (r < NN) {
                    if (r16 < 8) asrc[(size_t)r * 8 + r16] = acc[rr];
                    else         adst[(size_t)r * 8 + (r16 - 8)] = acc[rr];
                }
            }
            lmax = fmaxf(lmax, __shfl_xor(lmax, 16));
            lmax = fmaxf(lmax, __shfl_xor(lmax, 32));
            if (g == 0 && r16 < 8) atomicMax(&smax[r16], f2u(lmax));   // LDS atomic
        }
    }

    if constexpr (DOPLACE) {
        #pragma unroll
        for (int k = 0; k < 4; ++k) {
            if (ppos[k] >= 0) {
                __builtin_nontemporal_store(pval[k], (unsigned long long*)&csrES[ppos[k]]);
            }
        }
    }
    __syncthreads();
    if (t < 8) atomicMax(&gmaxE[t], smax[t]);   // 8 global atomics per block
}

// ---------------- CSR build ----------------
__global__ __launch_bounds__(256) void hist_rank(
    const int* __restrict__ dst, int* __restrict__ counts, int* __restrict__ rank) {
    int e = blockIdx.x * 256 + threadIdx.x;
    if (e >= NE) return;
    int d = dst[e];
    if ((unsigned)d >= NN) d = 0;
    rank[e] = atomicAdd(&counts[d], 1);
}

__global__ __launch_bounds__(256) void block_sum(const int* __restrict__ counts,
                                                 int* __restrict__ bsum) {
    __shared__ int red[256];
    int t = threadIdx.x, i = blockIdx.x * 256 + t;
    red[t] = (i < NN) ? counts[i] : 0;
    __syncthreads();
    for (int s = 128; s > 0; s >>= 1) {
        if (t < s) red[t] += red[t + s];
        __syncthreads();
    }
    if (t == 0) bsum[blockIdx.x] = red[0];
}

__global__ __launch_bounds__(256) void scan_bsum(const int* __restrict__ bsum,
                                                 int* __restrict__ boff) {
    __shared__ int sh[256];
    int t = threadIdx.x;
    int v = (t < SCAN_B) ? bsum[t] : 0;
    sh[t] = v;
    __syncthreads();
    for (int d = 1; d < 256; d <<= 1) {
        int u = (t >= d) ? sh[t - d] : 0;
        __syncthreads();
        sh[t] += u;
        __syncthreads();
    }
    if (t < SCAN_B) boff[t] = sh[t] - v;   // exclusive
}

__global__ __launch_bounds__(256) void scan_final(
    const int* __restrict__ counts, const int* __restrict__ boff,
    int* __restrict__ off)
{
    __shared__ int sh[256];
    int t = threadIdx.x, i = blockIdx.x * 256 + t;
    int v = (i < NN) ? counts[i] : 0;
    sh[t] = v;
    __syncthreads();
    for (int d = 1; d < 256; d <<= 1) {
        int u = (t >= d) ? sh[t - d] : 0;
        __syncthreads();
        sh[t] += u;
        __syncthreads();
    }
    if (i < NN) {
        int o = boff[blockIdx.x] + sh[t] - v;
        off[i] = o;
        if (i == NN - 1) off[NN] = o + v;
    }
}

// H-row gather + FMA helper
__device__ __forceinline__ void gather_fma(
    const __half* __restrict__ H16, int sk, int ql, float pm,
    float4& accA, float4& accB)
{
    float4 raw = *(const float4*)&H16[(size_t)sk * 128 + ql * 8];
    const __half2* ph = (const __half2*)&raw;
    const float2 f0 = __half22float2(ph[0]);
    const float2 f1 = __half22float2(ph[1]);
    const float2 f2 = __half22float2(ph[2]);
    const float2 f3 = __half22float2(ph[3]);
    accA.x = fmaf(f0.x, pm, accA.x);
    accA.y = fmaf(f0.y, pm, accA.y);
    accA.z = fmaf(f1.x, pm, accA.z);
    accA.w = fmaf(f1.y, pm, accA.w);
    accB.x = fmaf(f2.x, pm, accB.x);
    accB.y = fmaf(f2.y, pm, accB.y);
    accB.z = fmaf(f3.x, pm, accB.z);
    accB.w = fmaf(f3.y, pm, accB.w);
}

// ---------------- SINGLE-PASS per-node softmax + aggregate (one wave per node) ----------------
// Fixed safe max M = lrelu(gmax[h] + adst[d,h]). 16 edges per iteration (two
// 8-edge sub-chunks) -> 4 independent H-row gathers in flight + 2 csrES + 2
// asrc prefetches (MLP vs latency-bound gather). All shfl sites wave-uniform.
template<typename OT, bool NTOUT>
__global__ __launch_bounds__(256) void node_fused(
    const int* __restrict__ off, const int2* __restrict__ csrES,
    const float* __restrict__ asrc, const float* __restrict__ adst,
    const unsigned int* __restrict__ gmaxE,
    const __half* __restrict__ H16, const float* __restrict__ bias,
    float* __restrict__ alpha, OT* __restrict__ out)
{
    __shared__ float pcache[4][ECAP * 8];   // per-wave unnormalized exp [i][h]
    __shared__ int2  scache[4][ECAP];       // per-wave {e, s}
    const int w = threadIdx.x >> 6;         // wave within block
    int wid = (blockIdx.x * 256 + threadIdx.x) >> 6;
    if (wid >= NN) return;
    const int lane = threadIdx.x & 63;
    const int n = wid;
    const int p0 = off[n], p1 = off[n + 1];
    const int deg = p1 - p0;
    const int h = lane & 7;      // head (stat lanes: lane = el*8+h)
    const int el = lane >> 3;    // edge-local slot 0..7
    const float ad = adst[n * 8 + h];
    const float M = lrelu(u2f(gmaxE[h]) + ad);   // safe upper bound for this node/head

    const int q  = lane >> 4;    // gather quarter
    const int ql = lane & 15;    // channels ql*8..ql*8+7
    const int hq = ql >> 1;      // head of this channel group

    float l = 0.f;
    float4 accA = make_float4(0.f, 0.f, 0.f, 0.f);
    float4 accB = make_float4(0.f, 0.f, 0.f, 0.f);

    if (deg > 0) {
        const int pEnd = p1 - 1;
        int2  esA = csrES[min(p0 + el, pEnd)];        // sub-chunk A prefetch
        int2  esB = csrES[min(p0 + 8 + el, pEnd)];    // sub-chunk B prefetch
        float avA = asrc[(size_t)esA.y * 8 + h];
        float avB = asrc[(size_t)esB.y * 8 + h];
        for (int base = 0; base < deg; base += 16) {
            int2 esA_nx = csrES[min(p0 + base + 16 + el, pEnd)];
            int2 esB_nx = csrES[min(p0 + base + 24 + el, pEnd)];
            const int iA = base + el, iB = base + 8 + el;
            const int sA = esA.y, sB = esB.y;
            float pA = 0.f, pB = 0.f;
            if (iA < deg) {
                pA = __expf(lrelu(avA + ad) - M);
                l += pA;
                if (iA < ECAP) {
                    pcache[w][iA * 8 + h] = pA;
                    if (h == 0) scache[w][iA] = esA;
                }
            }
            if (iB < deg) {
                pB = __expf(lrelu(avB + ad) - M);
                l += pB;
                if (iB < ECAP) {
                    pcache[w][iB * 8 + h] = pB;
                    if (h == 0) scache[w][iB] = esB;
                }
            }
            const int cntA = min(8, deg - base);                 // >= 1
            const int cntB = min(8, max(0, deg - base - 8));     // may be 0
            {   // A step 0 (always)
                const int kc = min(q, cntA - 1);
                const float pk = __shfl(pA, kc * 8 + hq);
                const int   sk = __shfl(sA, kc * 8);
                gather_fma(H16, sk, ql, (q < cntA) ? pk : 0.f, accA, accB);
            }
            if (cntA > 4) {   // wave-uniform
                const int kw = 4 + q, kc = min(kw, cntA - 1);
                const float pk = __shfl(pA, kc * 8 + hq);
                const int   sk = __shfl(sA, kc * 8);
                gather_fma(H16, sk, ql, (kw < cntA) ? pk : 0.f, accA, accB);
            }
            if (cntB > 0) {   // wave-uniform
                const int kc = min(q, cntB - 1);
                const float pk = __shfl(pB, kc * 8 + hq);
                const int   sk = __shfl(sB, kc * 8);
                gather_fma(H16, sk, ql, (q < cntB) ? pk : 0.f, accA, accB);
            }
            if (cntB > 4) {   // wave-uniform
                const int kw = 4 + q, kc = min(kw, cntB - 1);
                const float pk = __shfl(pB, kc * 8 + hq);
                const int   sk = __shfl(sB, kc * 8);
                gather_fma(H16, sk, ql, (kw < cntB) ? pk : 0.f, accA, accB);
            }
            avA = asrc[(size_t)esA_nx.y * 8 + h];
            avB = asrc[(size_t)esB_nx.y * 8 + h];
            esA = esA_nx;
            esB = esB_nx;
        }
    }
    // sum l across the 8 edge-slot groups
    l += __shfl_xor(l, 8);
    l += __shfl_xor(l, 16);
    l += __shfl_xor(l, 32);
    const float inv = 1.f / (l + 1e-16f);

    // alpha writes: cached edges from LDS (no shfl inside -> divergence safe)
    for (int i = el; i < deg && i < ECAP; i += 8) {
        int2 es = scache[w][i];
        __builtin_nontemporal_store(pcache[w][i * 8 + h] * inv,
                                    &alpha[(size_t)es.x * 8 + h]);
    }
    for (int i = ECAP + el; i < deg; i += 8) {         // rare overflow tail
        int2 es = csrES[p0 + i];
        float v = lrelu(asrc[es.y * 8 + h] + ad);
        __builtin_nontemporal_store(__expf(v - M) * inv,
                                    &alpha[(size_t)es.x * 8 + h]);
    }

    // combine quarters, normalize, bias, store
    const float invH = __shfl(inv, hq);    // inv for this channel group's head
    accA.x += __shfl_xor(accA.x, 16); accA.x += __shfl_xor(accA.x, 32);
    accA.y += __shfl_xor(accA.y, 16); accA.y += __shfl_xor(accA.y, 32);
    accA.z += __shfl_xor(accA.z, 16); accA.z += __shfl_xor(accA.z, 32);
    accA.w += __shfl_xor(accA.w, 16); accA.w += __shfl_xor(accA.w, 32);
    accB.x += __shfl_xor(accB.x, 16); accB.x += __shfl_xor(accB.x, 32);
    accB.y += __shfl_xor(accB.y, 16); accB.y += __shfl_xor(accB.y, 32);
    accB.z += __shfl_xor(accB.z, 16); accB.z += __shfl_xor(accB.z, 32);
    accB.w += __shfl_xor(accB.w, 16); accB.w += __shfl_xor(accB.w, 32);
    if (q == 0) {
        const float4 bva = *(const float4*)&bias[ql * 8];
        const float4 bvb = *(const float4*)&bias[ql * 8 + 4];
        const float o0 = accA.x * invH + bva.x, o1 = accA.y * invH + bva.y;
        const float o2 = accA.z * invH + bva.z, o3 = accA.w * invH + bva.w;
        const float o4 = accB.x * invH + bvb.x, o5 = accB.y * invH + bvb.y;
        const float o6 = accB.z * invH + bvb.z, o7 = accB.w * invH + bvb.w;
        if constexpr (sizeof(OT) == 4) {
            if constexpr (NTOUT) {
                f32x4 oa = {o0, o1, o2, o3}, ob = {o4, o5, o6, o7};
                __builtin_nontemporal_store(oa, (f32x4*)&out[(size_t)n * 128 + ql * 8]);
                __builtin_nontemporal_store(ob, (f32x4*)&out[(size_t)n * 128 + ql * 8 + 4]);
            } else {
                float4 oa = {o0, o1, o2, o3}, ob = {o4, o5, o6, o7};
                *(float4*)&out[(size_t)n * 128 + ql * 8]     = oa;
                *(float4*)&out[(size_t)n * 128 + ql * 8 + 4] = ob;
            }
        } else {
            __half2 p0h = __floats2half2_rn(o0, o1);
            __half2 p1h = __floats2half2_rn(o2, o3);
            __half2 p2h = __floats2half2_rn(o4, o5);
            __half2 p3h = __floats2half2_rn(o6, o7);
            u32x4 pk = {*(unsigned*)&p0h, *(unsigned*)&p1h, *(unsigned*)&p2h, *(unsigned*)&p3h};
            if constexpr (NTOUT) {
                __builtin_nontemporal_store(pk, (u32x4*)&out[(size_t)n * 128 + ql * 8]);
            } else {
                *(u32x4*)&out[(size_t)n * 128 + ql * 8] = pk;
            }
        }
    }
}

extern "C" void kernel_launch(void* const* d_in, const int* in_sizes, int n_in,
                              void* d_out, int out_size, void* d_ws, size_t ws_size,
                              hipStream_t stream)
{
    const float* x   = (const float*)d_in[0];
    const float* W1  = (const float*)d_in[1];
    const float* as1 = (const float*)d_in[2];
    const float* ad1 = (const float*)d_in[3];
    const float* b1  = (const float*)d_in[4];
    const float* W2  = (const float*)d_in[5];
    const float* as2 = (const float*)d_in[6];
    const float* ad2 = (const float*)d_in[7];
    const float* b2  = (const float*)d_in[8];
    const int*   ei  = (const int*)d_in[9];
    const int* srcp = ei;
    const int* dstp = ei + NE;

    float* outx   = (float*)d_out;            // [NN*128]
    float* alpha1 = outx + (size_t)NN * 128;  // [NE*8]
    float* alpha2 = alpha1 + (size_t)NE * 8;  // [NE*8]

    __half* h16 = (__half*)d_ws;                        // NN*128 halves
    __half* x1h = h16 + (size_t)NN * 128;               // NN*128 halves
    __half* wt1 = x1h + (size_t)NN * 128;               // 144*128 halves
    __half* wt2 = wt1 + (size_t)144 * 128;              // 144*128 halves
    float* asrc = (float*)(wt2 + (size_t)144 * 128);    // NN*8
    float* adst = asrc + (size_t)NN * 8;                // NN*8
    int* counts = (int*)(adst + (size_t)NN * 8);        // NN
    int* off    = counts + NN;                           // NN+1
    int* rank   = off + NN + 1;                          // NE
    int2* csrES = (int2*)(rank + NE);                    // NE int2
    int* bsum   = (int*)(csrES + NE);                    // SCAN_B
    int* boff   = bsum + SCAN_B;                         // SCAN_B
    unsigned int* gm1 = (unsigned int*)(boff + SCAN_B);  // 8
    unsigned int* gm2 = gm1 + 8;                         // 8

    int gemmGrid = (NN + 63) / 64;         // 782; also covers 782*1024 >= NE placements
    int nodeGrid = (NN + 3) / 4;           // 4 waves (nodes) per 256-thread block
    int edgeGrid = (NE + 255) / 256;

    // ---- fused prep (zero counts + gmax init + both WTaug) + CSR build ----
    prep_all<<<SCAN_B, 256, 0, stream>>>(W1, as1, ad1, wt1, W2, as2, ad2, wt2, counts, gm1, gm2);
    hist_rank<<<edgeGrid, 256, 0, stream>>>(dstp, counts, rank);
    block_sum<<<SCAN_B, 256, 0, stream>>>(counts, bsum);
    scan_bsum<<<1, 256, 0, stream>>>(bsum, boff);
    scan_final<<<SCAN_B, 256, 0, stream>>>(counts, boff, off);

    // ---- layer 1 (gemm fused with CSR placement) ----
    mfma_gemm<true, true><<<gemmGrid, 256, 0, stream>>>(
        x, wt1, h16, asrc, adst, gm1, srcp, dstp, rank, off, csrES);
    node_fused<__half, false><<<nodeGrid, 256, 0, stream>>>(off, csrES, asrc, adst, gm1, h16, b1, alpha1, x1h);

    // ---- layer 2 ----
    mfma_gemm<false, false><<<gemmGrid, 256, 0, stream>>>(
        x1h, wt2, h16, asrc, adst, gm2, nullptr, nullptr, nullptr, nullptr, nullptr);
    node_fused<float, true><<<nodeGrid, 256, 0, stream>>>(off, csrES, asrc, adst, gm2, h16, b2, alpha2, outx);
}